// Round 7
// baseline (157.347 us; speedup 1.0000x reference)
//
#include <hip/hip_runtime.h>
#include <hip/hip_bf16.h>

// Problem: B=2, C=256, H=W=64 -> N=4096 spatial, 8 heads, d=32.
// R7: (0) wcvt pre-converts w_qkv/w_proj to bf16 (QSCALE folded into Q rows).
// (1) qkv: grid(128 n-tiles of 32, 2), block 512; x^T panel staged ONCE,
//     6 o-tile-pair loop with direct-global B-fragments (no LDS for w).
// (2) attn unchanged from R6 (73.6us, MfmaUtil 38%).
// (3) proj: stage a^T only; w fragments direct from global bf16.

typedef __bf16 bf16;
typedef __bf16 bf16x4 __attribute__((ext_vector_type(4)));
typedef __bf16 bf16x8 __attribute__((ext_vector_type(8)));
typedef float  f32x4  __attribute__((ext_vector_type(4)));
typedef short  s16x4  __attribute__((ext_vector_type(4)));

#if __has_builtin(__builtin_amdgcn_mfma_f32_16x16x16bf16_1k)
#define HAVE_MFMA16 1
#endif

#if __has_builtin(__builtin_amdgcn_exp2f)
#define EXP2(x) __builtin_amdgcn_exp2f(x)
#else
#define EXP2(x) exp2f(x)
#endif

#define NS 4096
#define QSCALE (0.17677669529663687f * 1.4426950408889634f)

static __device__ inline unsigned pack2(float a, float b) {
  union { bf16 h[2]; unsigned u; } v;
  v.h[0] = (bf16)a; v.h[1] = (bf16)b;
  return v.u;
}

// ---------------------------------------------------------------------------
// Kernel 0: weight conversion fp32 -> bf16. QSCALE folded into w_qkv rows
// o<256 (the Q block). grid 128, block 256, 8 elems/thread.
// ---------------------------------------------------------------------------
__global__ __launch_bounds__(256) void wcvt(
    const float* __restrict__ wq, const float* __restrict__ wp,
    bf16* __restrict__ wqb, bf16* __restrict__ wpb)
{
  const int bid = blockIdx.x, t = threadIdx.x;
  if (bid < 96) {
    const int i = (bid * 256 + t) * 8;           // 0 .. 196607
    const float sc = (i < 65536) ? QSCALE : 1.0f;
    f32x4 a = *(const f32x4*)(wq + i);
    f32x4 b = *(const f32x4*)(wq + i + 4);
    bf16x8 o;
#pragma unroll
    for (int j = 0; j < 4; j++) { o[j] = (bf16)(a[j] * sc); o[4 + j] = (bf16)(b[j] * sc); }
    *(bf16x8*)(wqb + i) = o;
  } else {
    const int i = ((bid - 96) * 256 + t) * 8;    // 0 .. 65535
    f32x4 a = *(const f32x4*)(wp + i);
    f32x4 b = *(const f32x4*)(wp + i + 4);
    bf16x8 o;
#pragma unroll
    for (int j = 0; j < 4; j++) { o[j] = (bf16)a[j]; o[4 + j] = (bf16)b[j]; }
    *(bf16x8*)(wpb + i) = o;
  }
}

// ---------------------------------------------------------------------------
// Kernel 1: qkv. grid (128 n-tiles of 32, 2 b), block 512 (8 waves).
// Stage x^T panel (32n x 256c bf16) once; loop op=0..5 over o-tile pairs:
// wave-group (wv>>2) handles o-tile ot = op*2 + (wv>>2); within group,
// wave g=wv&3 covers o = ot*64 + g*16 + lb. B-frags (w) read directly from
// global bf16 (L2-hot). Q,K scatter-stored (b,h,n,d); V via LDS transpose
// to (b,h,d,n).
// ---------------------------------------------------------------------------
__global__ __launch_bounds__(512) void qkv_fused(
    const float* __restrict__ x, const bf16* __restrict__ wqb,
    const float* __restrict__ bias,
    bf16* __restrict__ qbuf, bf16* __restrict__ kbuf, bf16* __restrict__ vbuf)
{
  __shared__ bf16 As[32 * 264];     // x^T panel [n_local][c], stride 264
  __shared__ bf16 Vt2[2][64 * 40];  // per-group V-transpose [o_loc][n_loc]
  const int n0 = blockIdx.x * 32, b = blockIdx.z ? 1 : blockIdx.y;
  // grid is (128, 2, 1): decode b from y
  const int bb = blockIdx.y;
  const int t = threadIdx.x;
  const int wv = t >> 6, L = t & 63, quad = L >> 4, lb = L & 15;
  const int grp = wv >> 2, g = wv & 3;
  (void)b;

  // stage x^T: 2 passes; thread handles c-pair (t>>3), n-chunk (t&7)*4.
  {
    unsigned* A32 = (unsigned*)As;
    const int nj = (t & 7) * 4;
    const int cpair = t >> 3;            // 0..63
#pragma unroll
    for (int pass = 0; pass < 2; pass++) {
      const int c = pass * 128 + cpair * 2;
      const float* xr = x + ((size_t)(bb * 256 + c)) * NS + n0 + nj;
      f32x4 va = *(const f32x4*)xr;
      f32x4 vb = *(const f32x4*)(xr + NS);
#pragma unroll
      for (int i = 0; i < 4; i++)
        A32[(nj + i) * 132 + pass * 64 + cpair] = pack2(va[i], vb[i]);
    }
  }
  __syncthreads();

#pragma unroll
  for (int op = 0; op < 6; op++) {
    const int ot = op * 2 + grp;
    const int o = ot * 64 + g * 16 + lb;
    f32x4 acc[2] = {};
#pragma unroll
    for (int ks = 0; ks < 8; ks++) {
      const bf16x8 bfr = *(const bf16x8*)(wqb + (size_t)o * 256 + ks * 32 + quad * 8);
#pragma unroll
      for (int a = 0; a < 2; a++) {
        const bf16x8 afr = *(const bf16x8*)&As[(a * 16 + lb) * 264 + ks * 32 + quad * 8];
        acc[a] = __builtin_amdgcn_mfma_f32_16x16x32_bf16(afr, bfr, acc[a], 0, 0, 0);
      }
    }

    const int comp = ot >> 2;  // uniform across block (both ot of pair match)
    const float bv = bias[o] * (comp == 0 ? QSCALE : 1.0f);
    if (comp < 2) {
      bf16* dst = (comp == 0) ? qbuf : kbuf;
      const int hh = (o & 255) >> 5, dd = o & 31;
      const size_t base = ((size_t)bb * 8 + hh) * NS;
#pragma unroll
      for (int a = 0; a < 2; a++)
#pragma unroll
        for (int r = 0; r < 4; r++) {
          const int n = n0 + a * 16 + quad * 4 + r;
          dst[(base + n) * 32 + dd] = (bf16)(acc[a][r] + bv);
        }
    } else {
      // V: transpose via LDS to (b,h,d,n)
#pragma unroll
      for (int a = 0; a < 2; a++) {
        bf16x4 pk;
#pragma unroll
        for (int r = 0; r < 4; r++) pk[r] = (bf16)(acc[a][r] + bv);
        *(bf16x4*)&Vt2[grp][(g * 16 + lb) * 40 + a * 16 + quad * 4] = pk;
      }
      __syncthreads();
      {
        const int grp2 = t >> 8, u = t & 255;
        const int row = u >> 2, nc = (u & 3) * 8;
        const int ot2 = op * 2 + grp2;
        const int o2 = ot2 * 64 + row;
        const int hh2 = (o2 & 255) >> 5, dd2 = o2 & 31;
        bf16x8 v = *(const bf16x8*)&Vt2[grp2][row * 40 + nc];
        *(bf16x8*)(vbuf + (((size_t)bb * 8 + hh2) * 32 + dd2) * NS + n0 + nc) = v;
      }
      __syncthreads();
    }
  }
}

// ---------------------------------------------------------------------------
// Kernel 2: attn (unchanged from R6). grid (NS/128, B*8), block 512.
// ---------------------------------------------------------------------------
#define VT_OFF 2560                 // 64*40
#define KV_SZ  (2560 + 32 * 72)

__global__ __launch_bounds__(512) void attn_kernel(
    const bf16* __restrict__ qbuf, const bf16* __restrict__ kbuf,
    const bf16* __restrict__ vbuf, bf16* __restrict__ abuf)
{
  __shared__ bf16 KV[2][KV_SZ];
#ifndef HAVE_MFMA16
  __shared__ bf16 Ps[8][16 * 72];
#endif

  const int qb = blockIdx.x;
  const int bh = blockIdx.y;
  const bf16* Q  = qbuf + (size_t)bh * NS * 32;
  const bf16* K  = kbuf + (size_t)bh * NS * 32;
  const bf16* Vt = vbuf + (size_t)bh * 32 * NS;

  const int t = threadIdx.x;
  const int wv = t >> 6, L = t & 63, quad = L >> 4, lb = L & 15;
  const int qrow = qb * 128 + wv * 16;

  const bf16x8 qfrag = *(const bf16x8*)(Q + (size_t)(qrow + lb) * 32 + quad * 8);

  const int u = t & 255;
  const bool kside = t < 256;
  const int soff = kside ? ((u >> 2) * 40 + (u & 3) * 8)
                         : (VT_OFF + (u >> 3) * 72 + (u & 7) * 8);
  const bf16* gsrc = kside ? (K + (size_t)(u >> 2) * 32 + (u & 3) * 8)
                           : (Vt + (size_t)(u >> 3) * NS + (u & 7) * 8);
  const int gstep = kside ? 64 * 32 : 64;

  bf16x8 reg = *(const bf16x8*)gsrc;

  f32x4 oacc0 = {0.f, 0.f, 0.f, 0.f};
  f32x4 oacc1 = {0.f, 0.f, 0.f, 0.f};
  f32x4 oacc2 = {0.f, 0.f, 0.f, 0.f};
  const f32x4 zero4 = {0.f, 0.f, 0.f, 0.f};
#ifdef HAVE_MFMA16
  const s16x4 ones = {(short)0x3F80, (short)0x3F80, (short)0x3F80, (short)0x3F80};
#else
  float l_i = 0.f;
#endif

#pragma unroll 2
  for (int kt = 0; kt < 64; kt++) {
    const int buf = kt & 1;
    *(bf16x8*)&KV[buf][soff] = reg;
    __syncthreads();
    if (kt < 63) reg = *(const bf16x8*)(gsrc + (size_t)(kt + 1) * gstep);

    f32x4 st[4];
#pragma unroll
    for (int bi = 0; bi < 4; bi++) {
      const bf16x8 kf = *(const bf16x8*)&KV[buf][(bi * 16 + lb) * 40 + quad * 8];
      st[bi] = __builtin_amdgcn_mfma_f32_16x16x32_bf16(kf, qfrag, zero4, 0, 0, 0);
    }

#pragma unroll
    for (int bi = 0; bi < 4; bi++)
#pragma unroll
      for (int r = 0; r < 4; r++) st[bi][r] = EXP2(st[bi][r]);

#ifdef HAVE_MFMA16
#pragma unroll
    for (int bi = 0; bi < 4; bi++) {
      bf16x4 pb;
#pragma unroll
      for (int r = 0; r < 4; r++) pb[r] = (bf16)st[bi][r];
      const s16x4 pf = __builtin_bit_cast(s16x4, pb);
      const s16x4 vf0 = __builtin_bit_cast(s16x4,
          *(const bf16x4*)&KV[buf][VT_OFF + lb * 72 + bi * 16 + quad * 4]);
      const s16x4 vf1 = __builtin_bit_cast(s16x4,
          *(const bf16x4*)&KV[buf][VT_OFF + (16 + lb) * 72 + bi * 16 + quad * 4]);
      oacc0 = __builtin_amdgcn_mfma_f32_16x16x16bf16_1k(pf, vf0, oacc0, 0, 0, 0);
      oacc1 = __builtin_amdgcn_mfma_f32_16x16x16bf16_1k(pf, vf1, oacc1, 0, 0, 0);
      oacc2 = __builtin_amdgcn_mfma_f32_16x16x16bf16_1k(pf, ones, oacc2, 0, 0, 0);
    }
#else
    {
      float ls = 0.f;
#pragma unroll
      for (int bi = 0; bi < 4; bi++)
#pragma unroll
        for (int r = 0; r < 4; r++) ls += st[bi][r];
      l_i += ls;
      bf16* P = &Ps[wv][0];
#pragma unroll
      for (int bi = 0; bi < 4; bi++) {
        bf16x4 pk;
#pragma unroll
        for (int r = 0; r < 4; r++) pk[r] = (bf16)st[bi][r];
        *(bf16x4*)&P[lb * 72 + bi * 16 + quad * 4] = pk;
      }
#pragma unroll
      for (int ch = 0; ch < 2; ch++) {
        const bf16x8 pf  = *(const bf16x8*)&P[lb * 72 + ch * 32 + quad * 8];
        const bf16x8 vf0 = *(const bf16x8*)&KV[buf][VT_OFF + lb * 72 + ch * 32 + quad * 8];
        const bf16x8 vf1 = *(const bf16x8*)&KV[buf][VT_OFF + (16 + lb) * 72 + ch * 32 + quad * 8];
        oacc0 = __builtin_amdgcn_mfma_f32_16x16x32_bf16(pf, vf0, oacc0, 0, 0, 0);
        oacc1 = __builtin_amdgcn_mfma_f32_16x16x32_bf16(pf, vf1, oacc1, 0, 0, 0);
      }
    }
#endif
  }

  const int b_ = bh >> 3;
  const int hh = bh & 7;
#ifndef HAVE_MFMA16
  float lf = l_i;
  lf += __shfl_xor(lf, 16);
  lf += __shfl_xor(lf, 32);
#endif
#pragma unroll
  for (int r = 0; r < 4; r++) {
#ifdef HAVE_MFMA16
    const float lr = oacc2[r];
#else
    const float lr = __shfl(lf, (quad << 4) | (quad * 4 + r));
#endif
#if __has_builtin(__builtin_amdgcn_rcpf)
    const float inv = __builtin_amdgcn_rcpf(lr);
#else
    const float inv = 1.0f / lr;
#endif
    const int n = qrow + quad * 4 + r;
    bf16* dst = abuf + ((size_t)b_ * NS + n) * 256 + hh * 32;
    dst[lb]      = (bf16)(oacc0[r] * inv);
    dst[16 + lb] = (bf16)(oacc1[r] * inv);
  }
}

// ---------------------------------------------------------------------------
// Kernel 3: proj. grid (4 ch, 4 o, 32 = b*16+sHi), block 256.
// Stage only a^T (fused transpose); w fragments direct from global bf16.
// out[b][o][sHi*256+ch] = sum_c w[o][c]*abuf[b][c*16+sHi][ch] + bias[o].
// ---------------------------------------------------------------------------
__global__ __launch_bounds__(256) void proj_fused(
    const bf16* __restrict__ abuf, const bf16* __restrict__ wpb,
    const float* __restrict__ bias, float* __restrict__ out)
{
  __shared__ bf16 Bs[64 * 264];  // a^T tile [ch_local][c 0..255]
  const int ch0 = blockIdx.x * 64, o0 = blockIdx.y * 64;
  const int z = blockIdx.z, b = z >> 4, sHi = z & 15;
  const int t = threadIdx.x;
  const int wv = t >> 6, L = t & 63, quad = L >> 4, lb = L & 15;

  {
    const int chj = (t & 7) * 8;
#pragma unroll
    for (int p = 0; p < 8; p++) {
      const int c = p * 32 + (t >> 3);
      bf16x8 v = *(const bf16x8*)(abuf +
          ((size_t)b * NS + (size_t)c * 16 + sHi) * 256 + ch0 + chj);
#pragma unroll
      for (int i = 0; i < 8; i++) Bs[(chj + i) * 264 + c] = v[i];
    }
  }
  __syncthreads();

  f32x4 acc[4] = {};
#pragma unroll
  for (int ks = 0; ks < 8; ks++) {
    const bf16x8 bfr = *(const bf16x8*)&Bs[(wv * 16 + lb) * 264 + ks * 32 + quad * 8];
#pragma unroll
    for (int a = 0; a < 4; a++) {
      const bf16x8 afr = *(const bf16x8*)(wpb +
          (size_t)(o0 + a * 16 + lb) * 256 + ks * 32 + quad * 8);
      acc[a] = __builtin_amdgcn_mfma_f32_16x16x32_bf16(afr, bfr, acc[a], 0, 0, 0);
    }
  }

  const int ch = ch0 + wv * 16 + lb;
#pragma unroll
  for (int a = 0; a < 4; a++)
#pragma unroll
    for (int r = 0; r < 4; r++) {
      const int o = o0 + a * 16 + quad * 4 + r;
      out[((size_t)b * 256 + o) * NS + sHi * 256 + ch] = acc[a][r] + bias[o];
    }
}

// ---------------------------------------------------------------------------
extern "C" void kernel_launch(void* const* d_in, const int* in_sizes, int n_in,
                              void* d_out, int out_size, void* d_ws, size_t ws_size,
                              hipStream_t stream) {
  const float* x      = (const float*)d_in[0];
  const float* w_qkv  = (const float*)d_in[1];
  const float* b_qkv  = (const float*)d_in[2];
  const float* w_proj = (const float*)d_in[3];
  const float* b_proj = (const float*)d_in[4];
  float* out = (float*)d_out;

  char* ws = (char*)d_ws;
  const size_t MB = 1024 * 1024;
  bf16* qbuf = (bf16*)(ws);
  bf16* kbuf = (bf16*)(ws + 4 * MB);
  bf16* vbuf = (bf16*)(ws + 8 * MB);
  bf16* abuf = (bf16*)(ws + 12 * MB);
  bf16* wqb  = (bf16*)(ws + 16 * MB);
  bf16* wpb  = (bf16*)(ws + 17 * MB);

  wcvt<<<dim3(128), 256, 0, stream>>>(w_qkv, w_proj, wqb, wpb);
  qkv_fused<<<dim3(128, 2), 512, 0, stream>>>(x, wqb, b_qkv, qbuf, kbuf, vbuf);
  attn_kernel<<<dim3(32, 16), 512, 0, stream>>>(qbuf, kbuf, vbuf, abuf);
  proj_fused<<<dim3(4, 4, 32), 256, 0, stream>>>(abuf, wpb, b_proj, out);
}